// Round 8
// baseline (313.788 us; speedup 1.0000x reference)
//
#include <hip/hip_runtime.h>

typedef __attribute__((ext_vector_type(8))) short short8;
typedef __attribute__((ext_vector_type(4))) float f32x4;
typedef __attribute__((ext_vector_type(2))) unsigned int u32x2;

#define TTOK 10000
#define SBAR() __builtin_amdgcn_sched_barrier(0)

__device__ __forceinline__ unsigned pkbf(float lo, float hi){
  unsigned r;
  asm("v_cvt_pk_bf16_f32 %0, %1, %2" : "=v"(r) : "v"(lo), "v"(hi));
  return r;
}
__device__ __forceinline__ float ulo(unsigned p){ return __uint_as_float(p<<16); }
__device__ __forceinline__ float uhi(unsigned p){ return __uint_as_float(p&0xffff0000u); }

// AGPR pinning: park persistent state in the otherwise-idle accumulator half
// of the unified register file (rounds 2-7: arch half caps at 128 and spills
// while ~96 acc slots sit unused).
__device__ __forceinline__ unsigned a_put(unsigned v){
  unsigned r; asm("v_accvgpr_write_b32 %0, %1" : "=a"(r) : "v"(v)); return r;
}
__device__ __forceinline__ unsigned a_get(unsigned a){
  unsigned r; asm("v_accvgpr_read_b32 %0, %1" : "=v"(r) : "a"(a)); return r;
}

__device__ __forceinline__ unsigned short f2b(float f){
  unsigned x = __float_as_uint(f);
  unsigned r = (x + 0x7fffu + ((x>>16)&1u)) >> 16; // RNE
  return (unsigned short)r;
}

// ---------------- prep: bf16 weights, hb+t*tw seeds, c vector ----------------
__global__ void cnf_prep(const float* __restrict__ h, const float* __restrict__ Wx,
                         const float* __restrict__ wxt, const float* __restrict__ bx,
                         const float* __restrict__ Wh, const float* __restrict__ wht,
                         const float* __restrict__ bh, const float* __restrict__ W2,
                         float* __restrict__ hbt, float* __restrict__ cv,
                         unsigned short* __restrict__ wxb, unsigned short* __restrict__ w2b)
{
  const int b = blockIdx.x, t = threadIdx.x;
  if (b < 8) {
    for (int i=0;i<8;++i){ int idx = b*2048 + i*256 + t; wxb[idx] = f2b(Wx[idx]); }
  } else if (b < 16) {
    for (int i=0;i<8;++i){ int idx = (b-8)*2048 + i*256 + t; w2b[idx] = f2b(W2[idx]); }
  } else if (b < 18) {
    for (int i=0;i<4;++i){
      int idx = i*256 + t;
      int sb = (b-16)*8 + (idx>>7);
      int j  = idx & 127;
      float a = 0.f;
      for (int e2=0;e2<128;++e2) a += h[sb*128+e2]*Wh[j*128+e2];
      float base = a + bh[j] + bx[j];
      float tw   = wxt[j] + wht[j];
      for (int ti=0; ti<5; ++ti)
        hbt[(ti*16+sb)*128 + j] = base + 0.25f*(float)ti*tw;   // t in {0,.25,.5,.75,1}
    }
  } else {
    if (t < 128){
      float a = 0.f;
      for (int i=0;i<128;++i) a += W2[i*128+t]*Wx[t*128+i];
      cv[t] = a;
    }
  }
}

// ---------------- fused CNF main kernel ----------------
// Block: 256 thr = 4 waves; wave handles 16 rows (one 16-wide N-tile).
// (256,2): 128 arch + 128 acc per wave. zbp/ksp state pinned to AGPRs via
// inline asm; sched_barrier fences bound scheduler live-range stretching.
__global__ __launch_bounds__(256, 2) void cnf_main(
    const float* __restrict__ emb, const float* __restrict__ lp0,
    const float* __restrict__ b2g, const float* __restrict__ hbt,
    const float* __restrict__ cg,  const unsigned short* __restrict__ wxb,
    const unsigned short* __restrict__ w2b, float* __restrict__ out)
{
  __shared__ __align__(16) unsigned short sWx[16384];
  __shared__ __align__(16) unsigned short sW2[16384];
  __shared__ __align__(16) float sC[128];
  __shared__ __align__(16) float sB2[128];
  __shared__ __align__(16) float sH[5*2*128];            // hb+t*tw slices for block's <=2 sb values
  __shared__ __align__(16) unsigned short sT[4][1024];   // per-wave transpose buf (2KB)

  const int tid = threadIdx.x;
  const int rowbase = blockIdx.x*64;
  const int sb0 = rowbase/TTOK, sb1 = (rowbase+63)/TTOK;

  // stage weights into LDS with XOR swizzle (row&7)<<4 to kill b128-read bank conflicts
  for (int it=0; it<8; ++it){
    int L = it*4096 + tid*16;          // byte offset, 16B chunk inside one 256B row
    int hrow = L >> 8;
    int dst = L ^ ((hrow&7)<<4);
    *(int4*)((char*)sWx + dst) = *(const int4*)((const char*)wxb + L);
    *(int4*)((char*)sW2 + dst) = *(const int4*)((const char*)w2b + L);
  }
  if (tid < 128) sC[tid] = cg[tid]; else sB2[tid-128] = b2g[tid-128];
  for (int idx = tid; idx < 1280; idx += 256){
    int ti = idx >> 8, r = idx & 255;
    int j = r >> 7, e = r & 127;
    int sb = j ? sb1 : sb0;
    sH[idx] = hbt[(ti*16 + sb)*128 + e];
  }
  __syncthreads();

  const int w = tid>>6, l = tid&63, q = l&15, g = l>>4;
  char* tbB = (char*)&sT[w][0];
  const int cwB = q*16 + 8*(g&1) + 256*(g>>1);  // transpose write base (bytes), + htl*512
  const int crB = g*256 + q*16;                 // transpose read base (bytes), + kcl*1024
  const int wsw = (q&7)<<4;                     // weight-read swizzle
  const int qg  = q*256 + g*16;                 // weight-read lane offset (bytes)

  const int row = rowbase + 16*w + q;
  const int sb  = row/TTOK, tt = row - sb*TTOK;
  const int hsel = (sb == sb0) ? 0 : 128;

  unsigned zag[8][2];        // z state, packed bf16, AGPR-resident (16 acc regs)
  unsigned kag[8][2];        // RK4 running sum, packed bf16, AGPR-resident (16 acc regs)
  f32x4 wk[8];
  float dlt = 0.f;

  // z0 = emb[t] -> packed bf16 C-layout masters (slot e = 16*ht+4*g+r, col q)
  #pragma unroll
  for (int ht=0; ht<8; ++ht){
    f32x4 e4 = *(const f32x4*)(emb + tt*128 + 16*ht + 4*g);
    zag[ht][0] = a_put(pkbf(e4[0], e4[1]));
    zag[ht][1] = a_put(pkbf(e4[2], e4[3]));
    wk[ht] = (f32x4){0.f,0.f,0.f,0.f};
    kag[ht][0] = a_put(0u); kag[ht][1] = a_put(0u);
  }

  #pragma unroll 1
  for (int se=0; se<8; ++se){
    const int   s    = se>>2, e = se&3;
    const float coef = (e==0)?0.f:((e==3)?0.5f:0.25f); // z_eval = z_base + coef*k_prev
    const float we   = (e==1||e==2)?2.f:1.f;
    const int   ti   = 2*s + ((e==0)?0:((e<3)?1:2));

    // ---- phase 1: pack z_eval -> LDS transpose (XOR-swizzled) -> bf16 B-frags
    short8 zfr[4];
    #pragma unroll
    for (int hf=0; hf<2; ++hf){
      #pragma unroll
      for (int htl=0; htl<4; ++htl){
        const int ht = 4*hf + htl;
        unsigned zp0 = a_get(zag[ht][0]);
        unsigned zp1 = a_get(zag[ht][1]);
        u32x2 wv;
        if (e==0){
          wv[0] = zp0; wv[1] = zp1;                 // z_eval == zb, already bf16
        } else {
          float v0 = fmaf(coef, wk[ht][0], ulo(zp0));
          float v1 = fmaf(coef, wk[ht][1], uhi(zp0));
          float v2 = fmaf(coef, wk[ht][2], ulo(zp1));
          float v3 = fmaf(coef, wk[ht][3], uhi(zp1));
          wv[0] = pkbf(v0,v1); wv[1] = pkbf(v2,v3);
        }
        int W = htl*512 + cwB;
        W ^= ((W>>8)&7)<<4;
        *(u32x2*)(tbB + W) = wv;
      }
      #pragma unroll
      for (int kcl=0; kcl<2; ++kcl){
        int R = kcl*1024 + crB;
        R ^= ((R>>8)&7)<<4;
        zfr[2*hf+kcl] = *(const short8*)(tbB + R);
      }
      SBAR();
    }

    // ---- phase 2: seed acc with hb + t*tw (LDS slice)
    {
      const float* hb = &sH[ti*256 + hsel + 4*g];
      #pragma unroll
      for (int ht=0; ht<8; ++ht)
        wk[ht] = *(const f32x4*)(hb + 16*ht);
    }
    SBAR();

    // ---- phase 3: matmul1: pre = Wx . zT  (kc-fenced: <=8 weight frags in flight)
    #pragma unroll
    for (int kc=0; kc<4; ++kc){
      #pragma unroll
      for (int ht=0; ht<8; ++ht){
        const int off = (ht*4096 + kc*64 + qg) ^ wsw;
        short8 af = *(const short8*)((const char*)sWx + off);
        wk[ht] = __builtin_amdgcn_mfma_f32_16x16x32_bf16(af, zfr[kc], wk[ht], 0,0,0);
      }
      SBAR();
    }

    // ---- phase 4: softplus -> bf16 frags (via swizzled LDS transpose), sigmoid*c -> div
    short8 sfr[4];
    float dv = 0.f;
    #pragma unroll
    for (int hf=0; hf<2; ++hf){
      #pragma unroll
      for (int htl=0; htl<4; ++htl){
        const int ht = 4*hf+htl;
        f32x4 cc = *(const f32x4*)(&sC[16*ht + 4*g]);
        float spv[4];
        #pragma unroll
        for (int r=0;r<4;++r){
          float x  = wk[ht][r];
          float ax = __builtin_fabsf(x);
          float ea = __expf(-ax);
          float opa = 1.0f + ea;
          float rc = __builtin_amdgcn_rcpf(opa);
          float lg = __logf(opa);
          spv[r] = fmaxf(x,0.f) + lg;                 // softplus
          float sg = (x >= 0.f) ? rc : ea*rc;         // sigmoid
          dv += sg*cc[r];
        }
        int W = htl*512 + cwB;
        W ^= ((W>>8)&7)<<4;
        u32x2 wv = { pkbf(spv[0],spv[1]), pkbf(spv[2],spv[3]) };
        *(u32x2*)(tbB + W) = wv;
      }
      #pragma unroll
      for (int kcl=0; kcl<2; ++kcl){
        int R = kcl*1024 + crB;
        R ^= ((R>>8)&7)<<4;
        sfr[2*hf+kcl] = *(const short8*)(tbB + R);
      }
      SBAR();
    }
    dlt += we*dv;

    // ---- phase 5: matmul2: dz = W2 . spT  (acc seeded with b2; kc-fenced)
    #pragma unroll
    for (int ot=0; ot<8; ++ot)
      wk[ot] = *(const f32x4*)(&sB2[16*ot + 4*g]);
    SBAR();
    #pragma unroll
    for (int kc=0; kc<4; ++kc){
      #pragma unroll
      for (int ot=0; ot<8; ++ot){
        const int off = (ot*4096 + kc*64 + qg) ^ wsw;
        short8 af = *(const short8*)((const char*)sW2 + off);
        wk[ot] = __builtin_amdgcn_mfma_f32_16x16x32_bf16(af, sfr[kc], wk[ot], 0,0,0);
      }
      SBAR();
    }

    // ---- phase 6: RK4 accumulate into AGPR-resident packed bf16 kag
    if (e==0){
      #pragma unroll
      for (int ht=0;ht<8;++ht){
        kag[ht][0] = a_put(pkbf(wk[ht][0], wk[ht][1]));
        kag[ht][1] = a_put(pkbf(wk[ht][2], wk[ht][3]));
      }
    } else if (e<3){
      #pragma unroll
      for (int ht=0;ht<8;++ht){
        unsigned k0 = a_get(kag[ht][0]);
        unsigned k1 = a_get(kag[ht][1]);
        float a0 = fmaf(we, wk[ht][0], ulo(k0));
        float a1 = fmaf(we, wk[ht][1], uhi(k0));
        float a2 = fmaf(we, wk[ht][2], ulo(k1));
        float a3 = fmaf(we, wk[ht][3], uhi(k1));
        kag[ht][0] = a_put(pkbf(a0,a1));
        kag[ht][1] = a_put(pkbf(a2,a3));
      }
    } else {
      // z += (ks + k4)/12, straight into packed z state
      #pragma unroll
      for (int ht=0;ht<8;++ht){
        unsigned k0 = a_get(kag[ht][0]);
        unsigned k1 = a_get(kag[ht][1]);
        unsigned z0 = a_get(zag[ht][0]);
        unsigned z1 = a_get(zag[ht][1]);
        float a0 = fmaf(1.f/12.f, ulo(k0) + wk[ht][0], ulo(z0));
        float a1 = fmaf(1.f/12.f, uhi(k0) + wk[ht][1], uhi(z0));
        float a2 = fmaf(1.f/12.f, ulo(k1) + wk[ht][2], ulo(z1));
        float a3 = fmaf(1.f/12.f, uhi(k1) + wk[ht][3], uhi(z1));
        zag[ht][0] = a_put(pkbf(a0,a1));
        zag[ht][1] = a_put(pkbf(a2,a3));
      }
    }
    SBAR();
  }

  // ---- epilogue: reduce div partials over the 4 g-lanes, write log_pz1
  {
    float d = dlt*(1.f/12.f);
    d += __shfl_xor(d, 16, 64);
    d += __shfl_xor(d, 32, 64);
    if (g==0) out[row] = lp0[row] - d;
  }
}

extern "C" void kernel_launch(void* const* d_in, const int* in_sizes, int n_in,
                              void* d_out, int out_size, void* d_ws, size_t ws_size,
                              hipStream_t stream) {
  const float* h    = (const float*)d_in[0];
  const float* emb  = (const float*)d_in[1];
  const float* lp0  = (const float*)d_in[2];
  const float* Wx   = (const float*)d_in[3];
  const float* wxt  = (const float*)d_in[4];
  const float* bx   = (const float*)d_in[5];
  const float* Wh   = (const float*)d_in[6];
  const float* wht  = (const float*)d_in[7];
  const float* bh   = (const float*)d_in[8];
  const float* W2   = (const float*)d_in[9];
  const float* b2   = (const float*)d_in[10];
  float* out = (float*)d_out;

  char* ws = (char*)d_ws;
  float* hbt          = (float*)ws;            // 5*16*128 f32 = 40960 B
  float* cv           = (float*)(ws + 40960);  // 128 f32     = 512 B
  unsigned short* wxb = (unsigned short*)(ws + 41472); // 16384 bf16 = 32768 B
  unsigned short* w2b = (unsigned short*)(ws + 74240); // 16384 bf16 = 32768 B

  cnf_prep<<<19, 256, 0, stream>>>(h, Wx, wxt, bx, Wh, wht, bh, W2, hbt, cv, wxb, w2b);
  cnf_main<<<2500, 256, 0, stream>>>(emb, lp0, b2, hbt, cv, wxb, w2b, out);
}

// Round 9
// 291.356 us; speedup vs baseline: 1.0770x; 1.0770x over previous
//
#include <hip/hip_runtime.h>

typedef __attribute__((ext_vector_type(8))) short short8;
typedef __attribute__((ext_vector_type(4))) float f32x4;
typedef __attribute__((ext_vector_type(2))) unsigned int u32x2;

#define TTOK 10000
#define SBAR() __builtin_amdgcn_sched_barrier(0)

__device__ __forceinline__ unsigned pkbf(float lo, float hi){
  unsigned r;
  asm("v_cvt_pk_bf16_f32 %0, %1, %2" : "=v"(r) : "v"(lo), "v"(hi));
  return r;
}
__device__ __forceinline__ float ulo(unsigned p){ return __uint_as_float(p<<16); }
__device__ __forceinline__ float uhi(unsigned p){ return __uint_as_float(p&0xffff0000u); }

__device__ __forceinline__ unsigned short f2b(float f){
  unsigned x = __float_as_uint(f);
  unsigned r = (x + 0x7fffu + ((x>>16)&1u)) >> 16; // RNE
  return (unsigned short)r;
}

// ---------------- prep: bf16 weights, hb+t*tw seeds, c vector ----------------
__global__ void cnf_prep(const float* __restrict__ h, const float* __restrict__ Wx,
                         const float* __restrict__ wxt, const float* __restrict__ bx,
                         const float* __restrict__ Wh, const float* __restrict__ wht,
                         const float* __restrict__ bh, const float* __restrict__ W2,
                         float* __restrict__ hbt, float* __restrict__ cv,
                         unsigned short* __restrict__ wxb, unsigned short* __restrict__ w2b)
{
  const int b = blockIdx.x, t = threadIdx.x;
  if (b < 8) {
    for (int i=0;i<8;++i){ int idx = b*2048 + i*256 + t; wxb[idx] = f2b(Wx[idx]); }
  } else if (b < 16) {
    for (int i=0;i<8;++i){ int idx = (b-8)*2048 + i*256 + t; w2b[idx] = f2b(W2[idx]); }
  } else if (b < 18) {
    for (int i=0;i<4;++i){
      int idx = i*256 + t;
      int sb = (b-16)*8 + (idx>>7);
      int j  = idx & 127;
      float a = 0.f;
      for (int e2=0;e2<128;++e2) a += h[sb*128+e2]*Wh[j*128+e2];
      float base = a + bh[j] + bx[j];
      float tw   = wxt[j] + wht[j];
      for (int ti=0; ti<5; ++ti)
        hbt[(ti*16+sb)*128 + j] = base + 0.25f*(float)ti*tw;   // t in {0,.25,.5,.75,1}
    }
  } else {
    if (t < 128){
      float a = 0.f;
      for (int i=0;i<128;++i) a += W2[i*128+t]*Wx[t*128+i];
      cv[t] = a;
    }
  }
}

// ---------------- fused CNF main kernel ----------------
// Block: 256 thr = 4 waves; wave handles 16 rows (one 16-wide N-tile).
// Rounds 2-8 lesson: (256,2) => 128 arch + 128 acc. Structural fix this
// round: 4KB/wave transpose buffer holds the FULL z^T / sp^T, so matmuls
// read one 4-reg frag per kc just-in-time instead of keeping 32 frag regs
// live. Small broadcast tables (hb, c, b2) read from global/L2 to pay the
// LDS bill: 64KB weights + 16KB sT = 81920B exactly -> 2 blocks/CU.
__global__ __launch_bounds__(256, 2) void cnf_main(
    const float* __restrict__ emb, const float* __restrict__ lp0,
    const float* __restrict__ b2g, const float* __restrict__ hbt,
    const float* __restrict__ cg,  const unsigned short* __restrict__ wxb,
    const unsigned short* __restrict__ w2b, float* __restrict__ out)
{
  __shared__ __align__(16) unsigned short sWx[16384];
  __shared__ __align__(16) unsigned short sW2[16384];
  __shared__ __align__(16) unsigned short sT[4][2048];   // per-wave transpose buf (4KB)

  const int tid = threadIdx.x;
  const int rowbase = blockIdx.x*64;

  // stage weights into LDS with XOR swizzle (row&7)<<4 to kill b128-read bank conflicts
  for (int it=0; it<8; ++it){
    int L = it*4096 + tid*16;          // byte offset, 16B chunk inside one 256B row
    int hrow = L >> 8;
    int dst = L ^ ((hrow&7)<<4);
    *(int4*)((char*)sWx + dst) = *(const int4*)((const char*)wxb + L);
    *(int4*)((char*)sW2 + dst) = *(const int4*)((const char*)w2b + L);
  }
  __syncthreads();

  const int w = tid>>6, l = tid&63, q = l&15, g = l>>4;
  char* tbB = (char*)&sT[w][0];
  const int cwB = q*16 + 8*(g&1) + 256*(g>>1);  // transpose write base (bytes), + hf*2048 + htl*512
  const int crB = g*256 + q*16;                 // transpose read base (bytes), + kc*1024
  const int wsw = (q&7)<<4;                     // weight-read swizzle
  const int qg  = q*256 + g*16;                 // weight-read lane offset (bytes)

  const int row = rowbase + 16*w + q;
  const int sb  = row/TTOK, tt = row - sb*TTOK;

  unsigned zbp[8][2];        // z state, packed bf16 (16 VGPRs)
  unsigned ksp[8][2];        // RK4 running sum, packed bf16 (16 VGPRs)
  f32x4 wk[8];
  float dlt = 0.f;

  // z0 = emb[t] -> packed bf16 C-layout masters (slot e = 16*ht+4*g+r, col q)
  #pragma unroll
  for (int ht=0; ht<8; ++ht){
    f32x4 e4 = *(const f32x4*)(emb + tt*128 + 16*ht + 4*g);
    zbp[ht][0] = pkbf(e4[0], e4[1]);
    zbp[ht][1] = pkbf(e4[2], e4[3]);
    wk[ht] = (f32x4){0.f,0.f,0.f,0.f};
    ksp[ht][0] = 0u; ksp[ht][1] = 0u;
  }

  #pragma unroll 1
  for (int se=0; se<8; ++se){
    const int   s    = se>>2, e = se&3;
    const float coef = (e==0)?0.f:((e==3)?0.5f:0.25f); // z_eval = z_base + coef*k_prev
    const float we   = (e==1||e==2)?2.f:1.f;
    const int   ti   = 2*s + ((e==0)?0:((e<3)?1:2));

    // ---- phase 1: pack z_eval -> full 4KB LDS transpose (XOR-swizzled), writes only
    #pragma unroll
    for (int hf=0; hf<2; ++hf){
      #pragma unroll
      for (int htl=0; htl<4; ++htl){
        const int ht = 4*hf + htl;
        u32x2 wv;
        if (e==0){
          wv[0] = zbp[ht][0]; wv[1] = zbp[ht][1];   // z_eval == zb, already bf16
        } else {
          float v0 = fmaf(coef, wk[ht][0], ulo(zbp[ht][0]));
          float v1 = fmaf(coef, wk[ht][1], uhi(zbp[ht][0]));
          float v2 = fmaf(coef, wk[ht][2], ulo(zbp[ht][1]));
          float v3 = fmaf(coef, wk[ht][3], uhi(zbp[ht][1]));
          wv[0] = pkbf(v0,v1); wv[1] = pkbf(v2,v3);
        }
        int W = hf*2048 + htl*512 + cwB;
        W ^= ((W>>8)&7)<<4;
        *(u32x2*)(tbB + W) = wv;
      }
      SBAR();
    }

    // ---- phase 2: seed acc with hb + t*tw (global, L2-resident)
    {
      const float* hb = hbt + (ti*16 + sb)*128 + 4*g;
      #pragma unroll
      for (int ht=0; ht<8; ++ht)
        wk[ht] = *(const f32x4*)(hb + 16*ht);
    }
    SBAR();

    // ---- phase 3: matmul1: pre = Wx . zT  (per-kc just-in-time frag read)
    #pragma unroll
    for (int kc=0; kc<4; ++kc){
      int R = kc*1024 + crB;
      R ^= ((R>>8)&7)<<4;
      short8 zf = *(const short8*)(tbB + R);
      #pragma unroll
      for (int ht=0; ht<8; ++ht){
        const int off = (ht*4096 + kc*64 + qg) ^ wsw;
        short8 af = *(const short8*)((const char*)sWx + off);
        wk[ht] = __builtin_amdgcn_mfma_f32_16x16x32_bf16(af, zf, wk[ht], 0,0,0);
      }
      SBAR();
    }

    // ---- phase 4: softplus -> sp^T into LDS (writes only), sigmoid*c -> div
    float dv = 0.f;
    #pragma unroll
    for (int hf=0; hf<2; ++hf){
      #pragma unroll
      for (int htl=0; htl<4; ++htl){
        const int ht = 4*hf+htl;
        f32x4 cc = *(const f32x4*)(cg + 16*ht + 4*g);
        float spv[4];
        #pragma unroll
        for (int r=0;r<4;++r){
          float x  = wk[ht][r];
          float ax = __builtin_fabsf(x);
          float ea = __expf(-ax);
          float opa = 1.0f + ea;
          float rc = __builtin_amdgcn_rcpf(opa);
          float lg = __logf(opa);
          spv[r] = fmaxf(x,0.f) + lg;                 // softplus
          float sg = (x >= 0.f) ? rc : ea*rc;         // sigmoid
          dv += sg*cc[r];
        }
        int W = hf*2048 + htl*512 + cwB;
        W ^= ((W>>8)&7)<<4;
        u32x2 wv = { pkbf(spv[0],spv[1]), pkbf(spv[2],spv[3]) };
        *(u32x2*)(tbB + W) = wv;
      }
      SBAR();
    }
    dlt += we*dv;

    // ---- phase 5: matmul2: dz = W2 . spT  (acc seeded with b2 from global)
    #pragma unroll
    for (int ot=0; ot<8; ++ot)
      wk[ot] = *(const f32x4*)(b2g + 16*ot + 4*g);
    SBAR();
    #pragma unroll
    for (int kc=0; kc<4; ++kc){
      int R = kc*1024 + crB;
      R ^= ((R>>8)&7)<<4;
      short8 sf = *(const short8*)(tbB + R);
      #pragma unroll
      for (int ot=0; ot<8; ++ot){
        const int off = (ot*4096 + kc*64 + qg) ^ wsw;
        short8 af = *(const short8*)((const char*)sW2 + off);
        wk[ot] = __builtin_amdgcn_mfma_f32_16x16x32_bf16(af, sf, wk[ot], 0,0,0);
      }
      SBAR();
    }

    // ---- phase 6: RK4 accumulate into packed bf16 ksp (wk = k_e; feeds next z_eval too)
    if (e==0){
      #pragma unroll
      for (int ht=0;ht<8;++ht){
        ksp[ht][0] = pkbf(wk[ht][0], wk[ht][1]);
        ksp[ht][1] = pkbf(wk[ht][2], wk[ht][3]);
      }
    } else if (e<3){
      #pragma unroll
      for (int ht=0;ht<8;++ht){
        float a0 = fmaf(we, wk[ht][0], ulo(ksp[ht][0]));
        float a1 = fmaf(we, wk[ht][1], uhi(ksp[ht][0]));
        float a2 = fmaf(we, wk[ht][2], ulo(ksp[ht][1]));
        float a3 = fmaf(we, wk[ht][3], uhi(ksp[ht][1]));
        ksp[ht][0] = pkbf(a0,a1);
        ksp[ht][1] = pkbf(a2,a3);
      }
    } else {
      // z += (ks + k4)/12, straight into packed z state
      #pragma unroll
      for (int ht=0;ht<8;++ht){
        float a0 = fmaf(1.f/12.f, ulo(ksp[ht][0]) + wk[ht][0], ulo(zbp[ht][0]));
        float a1 = fmaf(1.f/12.f, uhi(ksp[ht][0]) + wk[ht][1], uhi(zbp[ht][0]));
        float a2 = fmaf(1.f/12.f, ulo(ksp[ht][1]) + wk[ht][2], ulo(zbp[ht][1]));
        float a3 = fmaf(1.f/12.f, uhi(ksp[ht][1]) + wk[ht][3], uhi(zbp[ht][1]));
        zbp[ht][0] = pkbf(a0,a1);
        zbp[ht][1] = pkbf(a2,a3);
      }
    }
    SBAR();
  }

  // ---- epilogue: reduce div partials over the 4 g-lanes, write log_pz1
  {
    float d = dlt*(1.f/12.f);
    d += __shfl_xor(d, 16, 64);
    d += __shfl_xor(d, 32, 64);
    if (g==0) out[row] = lp0[row] - d;
  }
}

extern "C" void kernel_launch(void* const* d_in, const int* in_sizes, int n_in,
                              void* d_out, int out_size, void* d_ws, size_t ws_size,
                              hipStream_t stream) {
  const float* h    = (const float*)d_in[0];
  const float* emb  = (const float*)d_in[1];
  const float* lp0  = (const float*)d_in[2];
  const float* Wx   = (const float*)d_in[3];
  const float* wxt  = (const float*)d_in[4];
  const float* bx   = (const float*)d_in[5];
  const float* Wh   = (const float*)d_in[6];
  const float* wht  = (const float*)d_in[7];
  const float* bh   = (const float*)d_in[8];
  const float* W2   = (const float*)d_in[9];
  const float* b2   = (const float*)d_in[10];
  float* out = (float*)d_out;

  char* ws = (char*)d_ws;
  float* hbt          = (float*)ws;            // 5*16*128 f32 = 40960 B
  float* cv           = (float*)(ws + 40960);  // 128 f32     = 512 B
  unsigned short* wxb = (unsigned short*)(ws + 41472); // 16384 bf16 = 32768 B
  unsigned short* w2b = (unsigned short*)(ws + 74240); // 16384 bf16 = 32768 B

  cnf_prep<<<19, 256, 0, stream>>>(h, Wx, wxt, bx, Wh, wht, bh, W2, hbt, cv, wxb, w2b);
  cnf_main<<<2500, 256, 0, stream>>>(emb, lp0, b2, hbt, cv, wxb, w2b, out);
}

// Round 10
// 249.326 us; speedup vs baseline: 1.2585x; 1.1686x over previous
//
#include <hip/hip_runtime.h>

typedef __attribute__((ext_vector_type(8))) short short8;
typedef __attribute__((ext_vector_type(4))) float f32x4;
typedef __attribute__((ext_vector_type(2))) unsigned int u32x2;

#define TTOK 10000
#define SBAR() __builtin_amdgcn_sched_barrier(0)

__device__ __forceinline__ unsigned pkbf(float lo, float hi){
  unsigned r;
  asm("v_cvt_pk_bf16_f32 %0, %1, %2" : "=v"(r) : "v"(lo), "v"(hi));
  return r;
}
__device__ __forceinline__ float ulo(unsigned p){ return __uint_as_float(p<<16); }
__device__ __forceinline__ float uhi(unsigned p){ return __uint_as_float(p&0xffff0000u); }

__device__ __forceinline__ unsigned short f2b(float f){
  unsigned x = __float_as_uint(f);
  unsigned r = (x + 0x7fffu + ((x>>16)&1u)) >> 16; // RNE
  return (unsigned short)r;
}

// ---------------- prep: bf16 weights, hb+t*tw seeds, c vector ----------------
__global__ void cnf_prep(const float* __restrict__ h, const float* __restrict__ Wx,
                         const float* __restrict__ wxt, const float* __restrict__ bx,
                         const float* __restrict__ Wh, const float* __restrict__ wht,
                         const float* __restrict__ bh, const float* __restrict__ W2,
                         float* __restrict__ hbt, float* __restrict__ cv,
                         unsigned short* __restrict__ wxb, unsigned short* __restrict__ w2b)
{
  const int b = blockIdx.x, t = threadIdx.x;
  if (b < 8) {
    for (int i=0;i<8;++i){ int idx = b*2048 + i*256 + t; wxb[idx] = f2b(Wx[idx]); }
  } else if (b < 16) {
    for (int i=0;i<8;++i){ int idx = (b-8)*2048 + i*256 + t; w2b[idx] = f2b(W2[idx]); }
  } else if (b < 18) {
    for (int i=0;i<4;++i){
      int idx = i*256 + t;
      int sb = (b-16)*8 + (idx>>7);
      int j  = idx & 127;
      float a = 0.f;
      for (int e2=0;e2<128;++e2) a += h[sb*128+e2]*Wh[j*128+e2];
      float base = a + bh[j] + bx[j];
      float tw   = wxt[j] + wht[j];
      for (int ti=0; ti<5; ++ti)
        hbt[(ti*16+sb)*128 + j] = base + 0.25f*(float)ti*tw;   // t in {0,.25,.5,.75,1}
    }
  } else {
    if (t < 128){
      float a = 0.f;
      for (int i=0;i<128;++i) a += W2[i*128+t]*Wx[t*128+i];
      cv[t] = a;
    }
  }
}

// ---------------- fused CNF main kernel ----------------
// Rounds 2-9 lesson: 16 rows/wave x full 128-dim cannot fit the 128-arch-reg
// cap at (256,2); every mitigation spilled. Structural fix: 2 waves per
// 16-row tile, split along h/e. Wave hw owns h in [hw*64,hw*64+64) of mm1/
// softplus and the matching e-half of z-state. Full-K operands (z^T, sp^T)
// live in shared per-tile LDS buffers; __syncthreads (2/eval) sequences
// write->read. Arch ledger: zbp 8 + ksp 8 + wk 16 + frags ~20 + temps ~25
// ~= 75 << 128 -> no spill. LDS 64KB weights + 16KB bufs = 80KB, 2 blk/CU.
__global__ __launch_bounds__(256, 2) void cnf_main(
    const float* __restrict__ emb, const float* __restrict__ lp0,
    const float* __restrict__ b2g, const float* __restrict__ hbt,
    const float* __restrict__ cg,  const unsigned short* __restrict__ wxb,
    const unsigned short* __restrict__ w2b, float* __restrict__ out)
{
  __shared__ __align__(16) unsigned short sWx[16384];
  __shared__ __align__(16) unsigned short sW2[16384];
  __shared__ __align__(16) unsigned short sZ[2][2048];   // per-tile z^T (4KB)
  __shared__ __align__(16) unsigned short sP[2][2048];   // per-tile sp^T (4KB)

  const int tid = threadIdx.x;
  const int rowbase = blockIdx.x*32;

  // stage weights into LDS with XOR swizzle (row&7)<<4 (verified rounds 1-9)
  for (int it=0; it<8; ++it){
    int L = it*4096 + tid*16;
    int hrow = L >> 8;
    int dst = L ^ ((hrow&7)<<4);
    *(int4*)((char*)sWx + dst) = *(const int4*)((const char*)wxb + L);
    *(int4*)((char*)sW2 + dst) = *(const int4*)((const char*)w2b + L);
  }
  __syncthreads();

  const int w = tid>>6, tile = w>>1, hw = w&1, l = tid&63, q = l&15, g = l>>4;
  char* zB = (char*)&sZ[tile][0];
  char* pB = (char*)&sP[tile][0];
  const int cwB = q*16 + 8*(g&1) + 256*(g>>1);  // transpose write base (bytes), + slot*512
  const int crB = g*256 + q*16;                 // transpose read base (bytes), + kc*1024
  const int wsw = (q&7)<<4;                     // weight-read swizzle
  const int qg  = q*256 + g*16;                 // weight-read lane offset (bytes)
  const int hof = hw*64 + 4*g;                  // h/e base for this wave: + 16*j + r

  const int row = rowbase + tile*16 + q;
  const int sb  = row/TTOK, tt = row - sb*TTOK;

  unsigned zbp[4][2];        // z state (this wave's e-half), packed bf16 (8 VGPRs)
  unsigned ksp[4][2];        // RK4 running sum, packed bf16 (8 VGPRs)
  f32x4 wk[4];
  float dlt = 0.f;

  // z0 = emb[t] for this wave's e-half (slot e = hof + 16*j + r, col q)
  #pragma unroll
  for (int j=0; j<4; ++j){
    f32x4 e4 = *(const f32x4*)(emb + tt*128 + hof + 16*j);
    zbp[j][0] = pkbf(e4[0], e4[1]);
    zbp[j][1] = pkbf(e4[2], e4[3]);
    wk[j] = (f32x4){0.f,0.f,0.f,0.f};
    ksp[j][0] = 0u; ksp[j][1] = 0u;
  }

  #pragma unroll 1
  for (int se=0; se<8; ++se){
    const int   s    = se>>2, e = se&3;
    const float coef = (e==0)?0.f:((e==3)?0.5f:0.25f); // z_eval = z_base + coef*k_prev
    const float we   = (e==1||e==2)?2.f:1.f;
    const int   ti   = 2*s + ((e==0)?0:((e<3)?1:2));

    // ---- phase 1: pack z_eval (this wave's 4 slots) -> shared z^T buffer
    #pragma unroll
    for (int j=0; j<4; ++j){
      u32x2 wv;
      if (e==0){
        wv[0] = zbp[j][0]; wv[1] = zbp[j][1];
      } else {
        float v0 = fmaf(coef, wk[j][0], ulo(zbp[j][0]));
        float v1 = fmaf(coef, wk[j][1], uhi(zbp[j][0]));
        float v2 = fmaf(coef, wk[j][2], ulo(zbp[j][1]));
        float v3 = fmaf(coef, wk[j][3], uhi(zbp[j][1]));
        wv[0] = pkbf(v0,v1); wv[1] = pkbf(v2,v3);
      }
      int W = (hw*4+j)*512 + cwB;
      W ^= ((W>>8)&7)<<4;
      *(u32x2*)(zB + W) = wv;
    }
    SBAR();
    __syncthreads();   // partner wave's z^T half visible

    // ---- phase 2: seed acc with hb + t*tw (global, L2-resident)
    {
      const float* hb = hbt + (ti*16 + sb)*128 + hof;
      #pragma unroll
      for (int j=0; j<4; ++j)
        wk[j] = *(const f32x4*)(hb + 16*j);
    }
    SBAR();

    // ---- phase 3: matmul1 (h-half): pre = Wx[h-half] . zT(full K)
    #pragma unroll
    for (int kc=0; kc<4; ++kc){
      int R = kc*1024 + crB;
      R ^= ((R>>8)&7)<<4;
      short8 zf = *(const short8*)(zB + R);
      #pragma unroll
      for (int j=0; j<4; ++j){
        const int off = (((hw*4+j)*4096) + kc*64 + qg) ^ wsw;
        short8 af = *(const short8*)((const char*)sWx + off);
        wk[j] = __builtin_amdgcn_mfma_f32_16x16x32_bf16(af, zf, wk[j], 0,0,0);
      }
      SBAR();
    }

    // ---- phase 4: softplus -> sp^T half into shared buffer, sigmoid*c -> div
    float dv = 0.f;
    #pragma unroll
    for (int j=0; j<4; ++j){
      f32x4 cc = *(const f32x4*)(cg + hof + 16*j);
      float spv[4];
      #pragma unroll
      for (int r=0;r<4;++r){
        float x  = wk[j][r];
        float ax = __builtin_fabsf(x);
        float ea = __expf(-ax);
        float opa = 1.0f + ea;
        float rc = __builtin_amdgcn_rcpf(opa);
        float lg = __logf(opa);
        spv[r] = fmaxf(x,0.f) + lg;                 // softplus
        float sg = (x >= 0.f) ? rc : ea*rc;         // sigmoid
        dv += sg*cc[r];
      }
      int W = (hw*4+j)*512 + cwB;
      W ^= ((W>>8)&7)<<4;
      u32x2 wv = { pkbf(spv[0],spv[1]), pkbf(spv[2],spv[3]) };
      *(u32x2*)(pB + W) = wv;
    }
    dlt += we*dv;
    SBAR();
    __syncthreads();   // partner wave's sp^T half visible

    // ---- phase 5: matmul2 (o-half): dz = W2[o-half] . spT(full K), seeded b2
    #pragma unroll
    for (int j=0; j<4; ++j)
      wk[j] = *(const f32x4*)(b2g + hof + 16*j);
    SBAR();
    #pragma unroll
    for (int kc=0; kc<4; ++kc){
      int R = kc*1024 + crB;
      R ^= ((R>>8)&7)<<4;
      short8 sf = *(const short8*)(pB + R);
      #pragma unroll
      for (int j=0; j<4; ++j){
        const int off = (((hw*4+j)*4096) + kc*64 + qg) ^ wsw;
        short8 af = *(const short8*)((const char*)sW2 + off);
        wk[j] = __builtin_amdgcn_mfma_f32_16x16x32_bf16(af, sf, wk[j], 0,0,0);
      }
      SBAR();
    }

    // ---- phase 6: RK4 accumulate (this wave's e-half; wk = k_e)
    if (e==0){
      #pragma unroll
      for (int j=0;j<4;++j){
        ksp[j][0] = pkbf(wk[j][0], wk[j][1]);
        ksp[j][1] = pkbf(wk[j][2], wk[j][3]);
      }
    } else if (e<3){
      #pragma unroll
      for (int j=0;j<4;++j){
        float a0 = fmaf(we, wk[j][0], ulo(ksp[j][0]));
        float a1 = fmaf(we, wk[j][1], uhi(ksp[j][0]));
        float a2 = fmaf(we, wk[j][2], ulo(ksp[j][1]));
        float a3 = fmaf(we, wk[j][3], uhi(ksp[j][1]));
        ksp[j][0] = pkbf(a0,a1);
        ksp[j][1] = pkbf(a2,a3);
      }
    } else {
      // z += (ks + k4)/12
      #pragma unroll
      for (int j=0;j<4;++j){
        float a0 = fmaf(1.f/12.f, ulo(ksp[j][0]) + wk[j][0], ulo(zbp[j][0]));
        float a1 = fmaf(1.f/12.f, uhi(ksp[j][0]) + wk[j][1], uhi(zbp[j][0]));
        float a2 = fmaf(1.f/12.f, ulo(ksp[j][1]) + wk[j][2], ulo(zbp[j][1]));
        float a3 = fmaf(1.f/12.f, uhi(ksp[j][1]) + wk[j][3], uhi(zbp[j][1]));
        zbp[j][0] = pkbf(a0,a1);
        zbp[j][1] = pkbf(a2,a3);
      }
    }
    SBAR();
  }

  // ---- epilogue: g-reduce div partials, cross-wave combine via LDS (reuse zB)
  {
    float d = dlt;
    d += __shfl_xor(d, 16, 64);
    d += __shfl_xor(d, 32, 64);
    float* fDv = (float*)zB;
    if (g==0) fDv[hw*16 + q] = d;
    __syncthreads();
    if (hw==0 && g==0){
      float dt = (fDv[q] + fDv[16+q]) * (1.f/12.f);
      out[row] = lp0[row] - dt;
    }
  }
}

extern "C" void kernel_launch(void* const* d_in, const int* in_sizes, int n_in,
                              void* d_out, int out_size, void* d_ws, size_t ws_size,
                              hipStream_t stream) {
  const float* h    = (const float*)d_in[0];
  const float* emb  = (const float*)d_in[1];
  const float* lp0  = (const float*)d_in[2];
  const float* Wx   = (const float*)d_in[3];
  const float* wxt  = (const float*)d_in[4];
  const float* bx   = (const float*)d_in[5];
  const float* Wh   = (const float*)d_in[6];
  const float* wht  = (const float*)d_in[7];
  const float* bh   = (const float*)d_in[8];
  const float* W2   = (const float*)d_in[9];
  const float* b2   = (const float*)d_in[10];
  float* out = (float*)d_out;

  char* ws = (char*)d_ws;
  float* hbt          = (float*)ws;            // 5*16*128 f32 = 40960 B
  float* cv           = (float*)(ws + 40960);  // 128 f32     = 512 B
  unsigned short* wxb = (unsigned short*)(ws + 41472); // 16384 bf16 = 32768 B
  unsigned short* w2b = (unsigned short*)(ws + 74240); // 16384 bf16 = 32768 B

  cnf_prep<<<19, 256, 0, stream>>>(h, Wx, wxt, bx, Wh, wht, bh, W2, hbt, cv, wxb, w2b);
  cnf_main<<<5000, 256, 0, stream>>>(emb, lp0, b2, hbt, cv, wxb, w2b, out);
}